// Round 1
// 1166.451 us; speedup vs baseline: 1.1324x; 1.1324x over previous
//
#include <hip/hip_runtime.h>
#include <hip/hip_bf16.h>

// TinyGRU: x[2048,512] int -> emb[95,48] -> GRU(H=48) -> logits[.,.,95] (+ h_last)
// Strategy:
//  A) xg_table[95][144] = emb @ w_ih^T + b_ih   (token -> input-gate contribution, 55 KB in d_ws)
//  B) recurrence: 1 block (=1 wave) per batch row; lane j<48 owns gate rows {j,j+48,j+96};
//     w_hh rows live in 144 VGPRs; h broadcast via uniform LDS reads.
//     h_t is stashed in the first 48 floats of each 95-wide logits row of d_out.
//  C) logits: block of 256 threads = 64 positions; h staged to LDS (stride 49);
//     wave w computes vocab slice [24w,24w+24) with wave-uniform scalar w_out loads;
//     results assembled in LDS and written with fully coalesced float4 stores
//     (fixes the 3.6x write amplification of the per-thread-row scalar-store version).

#define BATCH 2048
#define SEQ   512
#define HDIM  48
#define VOCAB 95
#define G3    144   // 3*HDIM
#define LPOS  64    // positions per logits block

__device__ __forceinline__ float sigmoidf_(float x) {
    return 1.0f / (1.0f + __expf(-x));
}

// ---------------- Kernel A: xg_table precompute ----------------
__global__ void xg_precompute(const float* __restrict__ emb,
                              const float* __restrict__ w_ih,
                              const float* __restrict__ b_ih,
                              float* __restrict__ xg) {
    int v = blockIdx.x;    // 0..94
    int g = threadIdx.x;   // 0..143
    const float* e = emb + v * HDIM;      // wave-uniform -> scalar loads
    const float* w = w_ih + g * HDIM;     // per-lane
    float a0 = 0.f, a1 = 0.f, a2 = 0.f, a3 = 0.f;
    #pragma unroll
    for (int k = 0; k < HDIM; k += 4) {
        a0 = fmaf(w[k + 0], e[k + 0], a0);
        a1 = fmaf(w[k + 1], e[k + 1], a1);
        a2 = fmaf(w[k + 2], e[k + 2], a2);
        a3 = fmaf(w[k + 3], e[k + 3], a3);
    }
    xg[v * G3 + g] = b_ih[g] + ((a0 + a1) + (a2 + a3));
}

// ---------------- Kernel B: GRU recurrence (unchanged) ----------------
__global__ __launch_bounds__(64, 2)
void gru_rec(const int* __restrict__ x,
             const float* __restrict__ xg_table,
             const float* __restrict__ w_hh,
             const float* __restrict__ b_hh,
             float* __restrict__ out,       // logits region; rows [pos*95 .. pos*95+47] used as h stash
             float* __restrict__ hidden) {  // [BATCH*HDIM]
    const int row = blockIdx.x;
    const int j   = threadIdx.x;   // lane; active for j<48
    __shared__ float hsh[HDIM];

    // stationary weights: 3 gate rows of w_hh per lane -> 144 VGPRs
    float4 wr[12], wz[12], wn[12];
    float br = 0.f, bz = 0.f, bn = 0.f;
    float hj = 0.f;
    if (j < HDIM) {
        const float4* whr = (const float4*)(w_hh + (j         ) * HDIM);
        const float4* whz = (const float4*)(w_hh + (j +   HDIM) * HDIM);
        const float4* whn = (const float4*)(w_hh + (j + 2*HDIM) * HDIM);
        #pragma unroll
        for (int k = 0; k < 12; ++k) { wr[k] = whr[k]; wz[k] = whz[k]; wn[k] = whn[k]; }
        br = b_hh[j]; bz = b_hh[j + HDIM]; bn = b_hh[j + 2*HDIM];
        hsh[j] = 0.f;
    }
    __syncthreads();

    const int* xrow = x + row * SEQ;
    int tok = xrow[0];
    for (int t = 0; t < SEQ; ++t) {
        int tok_next = (t + 1 < SEQ) ? xrow[t + 1] : 0;
        float hnew = 0.f;
        if (j < HDIM) {
            const float* xg = xg_table + tok * G3;   // L1/L2-resident 55 KB table
            float xr = xg[j], xz = xg[j + HDIM], xn = xg[j + 2*HDIM];
            float accr = br, accz = bz, accn = bn;
            const float4* h4 = (const float4*)hsh;   // uniform addr -> broadcast reads
            #pragma unroll
            for (int k = 0; k < 12; ++k) {
                float4 hh = h4[k];
                accr = fmaf(wr[k].x, hh.x, accr); accr = fmaf(wr[k].y, hh.y, accr);
                accr = fmaf(wr[k].z, hh.z, accr); accr = fmaf(wr[k].w, hh.w, accr);
                accz = fmaf(wz[k].x, hh.x, accz); accz = fmaf(wz[k].y, hh.y, accz);
                accz = fmaf(wz[k].z, hh.z, accz); accz = fmaf(wz[k].w, hh.w, accz);
                accn = fmaf(wn[k].x, hh.x, accn); accn = fmaf(wn[k].y, hh.y, accn);
                accn = fmaf(wn[k].z, hh.z, accn); accn = fmaf(wn[k].w, hh.w, accn);
            }
            float r = sigmoidf_(xr + accr);
            float z = sigmoidf_(xz + accz);
            float n = tanhf(xn + r * accn);
            hnew = (1.0f - z) * n + z * hj;
            hj = hnew;
            // stash h_t in unused head of the 95-wide logits row
            out[((long)(row * SEQ + t)) * VOCAB + j] = hnew;
        }
        __syncthreads();               // single wave: cheap; orders LDS write vs next reads
        if (j < HDIM) hsh[j] = hnew;
        __syncthreads();
        tok = tok_next;
    }
    if (j < HDIM) hidden[row * HDIM + j] = hj;
}

// ---------------- Kernel C: logits projection (LDS-assembled, coalesced writes) ----------------
__global__ __launch_bounds__(256, 4)
void logits_k(const float* __restrict__ w_out,
              const float* __restrict__ b_out,
              float* __restrict__ out) {
    // Single LDS buffer, reused across phases:
    //   phase 1/2: padded h stage, [LPOS][49]      (64*49 = 3136 floats)
    //   phase 3/4: logits tile,    [LPOS][VOCAB]   (64*95 = 6080 floats = 24,320 B)
    __shared__ __align__(16) float lsm[LPOS * VOCAB];

    const long pos0 = (long)blockIdx.x * LPOS;
    const int  tid  = threadIdx.x;
    const int  lane = tid & 63;
    // wave index forced into an SGPR so vocab-slice bounds (and thus w_out
    // addresses) are provably wave-uniform -> s_load, not vector loads
    const int  wv   = __builtin_amdgcn_readfirstlane(tid >> 6);   // 0..3

    // Phase 1: stage h rows (first 48 floats of each 95-wide row) into LDS,
    // padded to stride 49 (odd) so per-lane row reads are bank-conflict-free.
    for (int i = tid; i < LPOS * HDIM; i += 256) {
        int p = i / HDIM;
        int k = i - p * HDIM;
        lsm[p * 49 + k] = out[(pos0 + p) * VOCAB + k];
    }
    __syncthreads();

    // Phase 2: thread owns position p = lane (all 4 waves cover the same 64
    // positions, each handling a different vocab slice); h row -> 48 VGPRs.
    const int p = lane;
    float h[HDIM];
    #pragma unroll
    for (int k = 0; k < HDIM; ++k) h[k] = lsm[p * 49 + k];
    __syncthreads();   // everyone done reading h before logits overwrite LDS

    // Phase 3: wave wv computes vocab slice [24*wv, min(95, 24*wv+24)).
    // Write at stride 95 (odd) -> lanes spread across all banks.
    const int v0 = wv * 24;
    const int v1 = (v0 + 24 < VOCAB) ? (v0 + 24) : VOCAB;
    for (int v = v0; v < v1; ++v) {
        const float* w = w_out + v * HDIM;   // wave-uniform -> scalar loads
        float a0 = 0.f, a1 = 0.f, a2 = 0.f, a3 = 0.f;
        #pragma unroll
        for (int k = 0; k < HDIM; k += 4) {
            a0 = fmaf(w[k + 0], h[k + 0], a0);
            a1 = fmaf(w[k + 1], h[k + 1], a1);
            a2 = fmaf(w[k + 2], h[k + 2], a2);
            a3 = fmaf(w[k + 3], h[k + 3], a3);
        }
        lsm[p * VOCAB + v] = b_out[v] + ((a0 + a1) + (a2 + a3));
    }
    __syncthreads();

    // Phase 4: fully coalesced float4 store of the contiguous 64x95 tile.
    float4*       dst = (float4*)(out + pos0 * VOCAB);
    const float4* src = (const float4*)lsm;
    for (int i = tid; i < (LPOS * VOCAB) / 4; i += 256)
        dst[i] = src[i];
}

extern "C" void kernel_launch(void* const* d_in, const int* in_sizes, int n_in,
                              void* d_out, int out_size, void* d_ws, size_t ws_size,
                              hipStream_t stream) {
    const int*   x     = (const int*)d_in[0];
    const float* emb   = (const float*)d_in[1];
    const float* w_ih  = (const float*)d_in[2];
    const float* w_hh  = (const float*)d_in[3];
    const float* b_ih  = (const float*)d_in[4];
    const float* b_hh  = (const float*)d_in[5];
    const float* w_out = (const float*)d_in[6];
    const float* b_out = (const float*)d_in[7];

    float* out    = (float*)d_out;
    float* hidden = out + (long)BATCH * SEQ * VOCAB;  // second tuple element
    float* xg     = (float*)d_ws;                     // 95*144*4 = 54,720 B

    xg_precompute<<<VOCAB, G3, 0, stream>>>(emb, w_ih, b_ih, xg);
    gru_rec<<<BATCH, 64, 0, stream>>>(x, xg, w_hh, b_hh, out, hidden);
    logits_k<<<(BATCH * SEQ) / LPOS, 256, 0, stream>>>(w_out, b_out, out);
}

// Round 2
// 1162.744 us; speedup vs baseline: 1.1360x; 1.0032x over previous
//
#include <hip/hip_runtime.h>
#include <hip/hip_bf16.h>

// TinyGRU: x[2048,512] int -> emb[95,48] -> GRU(H=48) -> logits[.,.,95] (+ h_last)
// Strategy:
//  A) xg_table[95][144] = emb @ w_ih^T + b_ih   (token -> input-gate contribution, 55 KB in d_ws)
//  B) recurrence: 1 block (=1 wave) per batch row; lane j<48 owns gate rows {j,j+48,j+96};
//     w_hh rows live in 144 VGPRs; h broadcast via uniform LDS reads.
//     NO __syncthreads in the loop: single-wave block, LDS ops are in-order per wave.
//     (The old per-step barriers forced s_waitcnt vmcnt(0) -> drained the global
//      h-store + xg loads every step: ~3300 cyc/step. That was the bottleneck.)
//     xg gate inputs for t+1 prefetched during step t.
//     h_t goes to a COMPACT stash in d_ws (201 MB) when ws_size allows; else falls
//     back to stashing in the logits rows (in-place, like before).
//  C) logits: block of 256 threads = 64 positions; h staged to LDS (stride 49);
//     wave w computes vocab slice [24w,24w+24) with wave-uniform scalar w_out loads;
//     tile assembled in LDS, written with coalesced float4 stores. With the compact
//     stash, `out` is write-only here (no read/write aliasing of the 398 MB region).

#define BATCH 2048
#define SEQ   512
#define HDIM  48
#define VOCAB 95
#define G3    144   // 3*HDIM
#define LPOS  64    // positions per logits block

__device__ __forceinline__ float sigmoidf_(float x) {
    return 1.0f / (1.0f + __expf(-x));
}
__device__ __forceinline__ float tanhf_(float x) {
    // tanh(x) = 1 - 2/(e^{2x}+1); stable at both infinities, ~ulp-level fp32 error
    return 1.0f - 2.0f / (__expf(2.0f * x) + 1.0f);
}

// ---------------- Kernel A: xg_table precompute ----------------
__global__ void xg_precompute(const float* __restrict__ emb,
                              const float* __restrict__ w_ih,
                              const float* __restrict__ b_ih,
                              float* __restrict__ xg) {
    int v = blockIdx.x;    // 0..94
    int g = threadIdx.x;   // 0..143
    const float* e = emb + v * HDIM;      // wave-uniform -> scalar loads
    const float* w = w_ih + g * HDIM;     // per-lane
    float a0 = 0.f, a1 = 0.f, a2 = 0.f, a3 = 0.f;
    #pragma unroll
    for (int k = 0; k < HDIM; k += 4) {
        a0 = fmaf(w[k + 0], e[k + 0], a0);
        a1 = fmaf(w[k + 1], e[k + 1], a1);
        a2 = fmaf(w[k + 2], e[k + 2], a2);
        a3 = fmaf(w[k + 3], e[k + 3], a3);
    }
    xg[v * G3 + g] = b_ih[g] + ((a0 + a1) + (a2 + a3));
}

// ---------------- Kernel B: GRU recurrence ----------------
__global__ __launch_bounds__(64, 2)
void gru_rec(const int* __restrict__ x,
             const float* __restrict__ xg_table,
             const float* __restrict__ w_hh,
             const float* __restrict__ b_hh,
             float* __restrict__ stash,     // h_t stash: compact ws (stride 48) or logits rows (stride 95)
             long sstride,
             float* __restrict__ hidden) {  // [BATCH*HDIM]
    const int row = blockIdx.x;
    const int j   = threadIdx.x;   // lane; active for j<48
    __shared__ float hsh[HDIM];

    // stationary weights: 3 gate rows of w_hh per lane -> 144 VGPRs
    float4 wr[12], wz[12], wn[12];
    float br = 0.f, bz = 0.f, bn = 0.f;
    float hj = 0.f;
    if (j < HDIM) {
        const float4* whr = (const float4*)(w_hh + (j         ) * HDIM);
        const float4* whz = (const float4*)(w_hh + (j +   HDIM) * HDIM);
        const float4* whn = (const float4*)(w_hh + (j + 2*HDIM) * HDIM);
        #pragma unroll
        for (int k = 0; k < 12; ++k) { wr[k] = whr[k]; wz[k] = whz[k]; wn[k] = whn[k]; }
        br = b_hh[j]; bz = b_hh[j + HDIM]; bn = b_hh[j + 2*HDIM];
        hsh[j] = 0.f;
    }
    __syncthreads();   // once, before the loop (orders initial hsh zeroing)

    const int* xrow = x + row * SEQ;
    // prefetch gate inputs for t=0
    int tok = xrow[0];
    float xr = 0.f, xz = 0.f, xn = 0.f;
    if (j < HDIM) {
        const float* xg0 = xg_table + tok * G3;
        xr = xg0[j]; xz = xg0[j + HDIM]; xn = xg0[j + 2*HDIM];
    }
    float* srow = stash + (long)row * SEQ * sstride + j;

    for (int t = 0; t < SEQ; ++t) {
        // prefetch next step's gate inputs (hides L2 latency under the FMA chain)
        int tok_next = (t + 1 < SEQ) ? xrow[t + 1] : 0;
        float xrn = 0.f, xzn = 0.f, xnn = 0.f;
        if (j < HDIM) {
            const float* xgn = xg_table + tok_next * G3;
            xrn = xgn[j]; xzn = xgn[j + HDIM]; xnn = xgn[j + 2*HDIM];
        }
        if (j < HDIM) {
            float accr = br, accz = bz, accn = bn;
            const float4* h4 = (const float4*)hsh;   // uniform addr -> broadcast reads
            #pragma unroll
            for (int k = 0; k < 12; ++k) {
                float4 hh = h4[k];
                accr = fmaf(wr[k].x, hh.x, accr); accr = fmaf(wr[k].y, hh.y, accr);
                accr = fmaf(wr[k].z, hh.z, accr); accr = fmaf(wr[k].w, hh.w, accr);
                accz = fmaf(wz[k].x, hh.x, accz); accz = fmaf(wz[k].y, hh.y, accz);
                accz = fmaf(wz[k].z, hh.z, accz); accz = fmaf(wz[k].w, hh.w, accz);
                accn = fmaf(wn[k].x, hh.x, accn); accn = fmaf(wn[k].y, hh.y, accn);
                accn = fmaf(wn[k].z, hh.z, accn); accn = fmaf(wn[k].w, hh.w, accn);
            }
            float r = sigmoidf_(xr + accr);
            float z = sigmoidf_(xz + accz);
            float n = tanhf_(xn + r * accn);
            float hnew = (1.0f - z) * n + z * hj;
            hj = hnew;
            srow[(long)t * sstride] = hnew;   // fire-and-forget global store
            hsh[j] = hnew;                    // ds_write; same-wave in-order vs next ds_read
        }
        xr = xrn; xz = xzn; xn = xnn;
    }
    if (j < HDIM) hidden[row * HDIM + j] = hj;
}

// ---------------- Kernel C: logits projection (LDS-assembled, coalesced writes) ----------------
__global__ __launch_bounds__(256, 4)
void logits_k(const float* __restrict__ w_out,
              const float* __restrict__ b_out,
              const float* __restrict__ stash,   // h stash (stride 48 compact, or 95 = in-place rows)
              long sstride,
              float* __restrict__ out) {
    // Single LDS buffer, reused across phases:
    //   phase 1/2: padded h stage, [LPOS][49]      (64*49 = 3136 floats)
    //   phase 3/4: logits tile,    [LPOS][VOCAB]   (64*95 = 6080 floats = 24,320 B)
    __shared__ __align__(16) float lsm[LPOS * VOCAB];

    const long pos0 = (long)blockIdx.x * LPOS;
    const int  tid  = threadIdx.x;
    const int  lane = tid & 63;
    // wave index forced into an SGPR so vocab-slice bounds (and thus w_out
    // addresses) are provably wave-uniform -> s_load, not vector loads
    const int  wv   = __builtin_amdgcn_readfirstlane(tid >> 6);   // 0..3

    // Phase 1: stage h rows into LDS, padded to stride 49 (odd) -> conflict-free.
    // With the compact stash (sstride=48) this read is perfectly contiguous.
    for (int i = tid; i < LPOS * HDIM; i += 256) {
        int p = i / HDIM;
        int k = i - p * HDIM;
        lsm[p * 49 + k] = stash[(pos0 + p) * sstride + k];
    }
    __syncthreads();

    // Phase 2: thread owns position p = lane (all 4 waves cover the same 64
    // positions, each handling a different vocab slice); h row -> 48 VGPRs.
    const int p = lane;
    float h[HDIM];
    #pragma unroll
    for (int k = 0; k < HDIM; ++k) h[k] = lsm[p * 49 + k];
    __syncthreads();   // everyone done reading h before logits overwrite LDS

    // Phase 3: wave wv computes vocab slice [24*wv, min(95, 24*wv+24)).
    // Write at stride 95 (odd) -> lanes spread across all banks.
    const int v0 = wv * 24;
    const int v1 = (v0 + 24 < VOCAB) ? (v0 + 24) : VOCAB;
    for (int v = v0; v < v1; ++v) {
        const float* w = w_out + v * HDIM;   // wave-uniform -> scalar loads
        float a0 = 0.f, a1 = 0.f, a2 = 0.f, a3 = 0.f;
        #pragma unroll
        for (int k = 0; k < HDIM; k += 4) {
            a0 = fmaf(w[k + 0], h[k + 0], a0);
            a1 = fmaf(w[k + 1], h[k + 1], a1);
            a2 = fmaf(w[k + 2], h[k + 2], a2);
            a3 = fmaf(w[k + 3], h[k + 3], a3);
        }
        lsm[p * VOCAB + v] = b_out[v] + ((a0 + a1) + (a2 + a3));
    }
    __syncthreads();

    // Phase 4: fully coalesced float4 store of the contiguous 64x95 tile.
    float4*       dst = (float4*)(out + pos0 * VOCAB);
    const float4* src = (const float4*)lsm;
    for (int i = tid; i < (LPOS * VOCAB) / 4; i += 256)
        dst[i] = src[i];
}

extern "C" void kernel_launch(void* const* d_in, const int* in_sizes, int n_in,
                              void* d_out, int out_size, void* d_ws, size_t ws_size,
                              hipStream_t stream) {
    const int*   x     = (const int*)d_in[0];
    const float* emb   = (const float*)d_in[1];
    const float* w_ih  = (const float*)d_in[2];
    const float* w_hh  = (const float*)d_in[3];
    const float* b_ih  = (const float*)d_in[4];
    const float* b_hh  = (const float*)d_in[5];
    const float* w_out = (const float*)d_in[6];
    const float* b_out = (const float*)d_in[7];

    float* out    = (float*)d_out;
    float* hidden = out + (long)BATCH * SEQ * VOCAB;  // second tuple element
    float* xg     = (float*)d_ws;                     // 95*144*4 = 54,720 B

    // compact h stash in workspace if it fits (201 MB); else stash in logits rows
    size_t xg_bytes = (((size_t)VOCAB * G3 * sizeof(float)) + 255) & ~(size_t)255;
    size_t stash_need = (size_t)BATCH * SEQ * HDIM * sizeof(float);
    float* stash;
    long   sstride;
    if (ws_size >= xg_bytes + stash_need) {
        stash   = (float*)((char*)d_ws + xg_bytes);
        sstride = HDIM;    // compact, dense
    } else {
        stash   = out;     // fallback: first 48 floats of each 95-wide logits row
        sstride = VOCAB;
    }

    xg_precompute<<<VOCAB, G3, 0, stream>>>(emb, w_ih, b_ih, xg);
    gru_rec<<<BATCH, 64, 0, stream>>>(x, xg, w_hh, b_hh, stash, sstride, hidden);
    logits_k<<<(BATCH * SEQ) / LPOS, 256, 0, stream>>>(w_out, b_out, stash, sstride, out);
}

// Round 3
// 1108.403 us; speedup vs baseline: 1.1917x; 1.0490x over previous
//
#include <hip/hip_runtime.h>

// TinyGRU: x[2048,512] int -> emb[95,48] -> GRU(H=48) -> logits[.,.,95] (+ h_last)
// R3: FUSED producer/consumer design.
//  A) xg_table[95][144] = emb @ w_ih^T + b_ih  (55 KB in d_ws)
//  B) gru_fused: 1 block = 1 batch row, 128 threads = 2 waves.
//       wave0 (producer): GRU recurrence; w_hh rows {j,j+48,j+96} pinned in 144 VGPRs
//                         (asm "+v" pin defeats the remat-into-loop that left VGPR=88
//                          and made R2's gru_rec re-load 576B/lane/step);
//                         h_t published to hbuf[t&1] in LDS.
//       wave1 (consumer): logits for h_t; w_out rows {lane, lane+64} pinned in 96 VGPRs;
//                         h_t broadcast-read from LDS; 380 B/step streamed to out
//                         (successive t contiguous per row -> clean full-line writes).
//     One __syncthreads per step pairs producer-bottom with consumer-top:
//       consumer reads parity t&1 strictly between barriers #t and #t+1;
//       producer rewrites that parity only after barrier #t+1 -> race-free.
//     No h stash, no separate logits kernel: 600 MB intermediate traffic removed;
//     out written exactly once. Both waves execute exactly SEQ barriers.

#define BATCH 2048
#define SEQ   512
#define HDIM  48
#define VOCAB 95
#define G3    144   // 3*HDIM

__device__ __forceinline__ float sigmoidf_(float x) {
    return 1.0f / (1.0f + __expf(-x));
}
__device__ __forceinline__ float tanhf_(float x) {
    // tanh(x) = 1 - 2/(e^{2x}+1); stable at both infinities, ~ulp-level fp32 error
    return 1.0f - 2.0f / (__expf(2.0f * x) + 1.0f);
}

// ---------------- Kernel A: xg_table precompute ----------------
__global__ void xg_precompute(const float* __restrict__ emb,
                              const float* __restrict__ w_ih,
                              const float* __restrict__ b_ih,
                              float* __restrict__ xg) {
    int v = blockIdx.x;    // 0..94
    int g = threadIdx.x;   // 0..143
    const float* e = emb + v * HDIM;      // wave-uniform -> scalar loads
    const float* w = w_ih + g * HDIM;     // per-lane
    float a0 = 0.f, a1 = 0.f, a2 = 0.f, a3 = 0.f;
    #pragma unroll
    for (int k = 0; k < HDIM; k += 4) {
        a0 = fmaf(w[k + 0], e[k + 0], a0);
        a1 = fmaf(w[k + 1], e[k + 1], a1);
        a2 = fmaf(w[k + 2], e[k + 2], a2);
        a3 = fmaf(w[k + 3], e[k + 3], a3);
    }
    xg[v * G3 + g] = b_ih[g] + ((a0 + a1) + (a2 + a3));
}

// pin a float4's components into VGPRs and make them opaque to rematerialization
#define PIN4(f) asm volatile("" : "+v"((f).x), "+v"((f).y), "+v"((f).z), "+v"((f).w))

// ---------------- Kernel B: fused GRU recurrence + logits ----------------
__global__ __launch_bounds__(128, 2)
void gru_fused(const int* __restrict__ x,
               const float* __restrict__ xg_table,
               const float* __restrict__ w_hh,
               const float* __restrict__ b_hh,
               const float* __restrict__ w_out,
               const float* __restrict__ b_out,
               float* __restrict__ out,       // [BATCH*SEQ*VOCAB]
               float* __restrict__ hidden) {  // [BATCH*HDIM]
    const int row  = blockIdx.x;
    const int tid  = threadIdx.x;
    const int lane = tid & 63;
    const int wid  = __builtin_amdgcn_readfirstlane(tid >> 6);  // wave-uniform 0/1

    __shared__ __align__(16) float hbuf[2][HDIM];   // double-buffered h_t

    float* orow = out + (long)row * SEQ * VOCAB;

    if (wid == 0) {
        // ================= producer: GRU recurrence =================
        const int j  = lane;
        const int jj = (j < HDIM) ? j : (j - HDIM);   // branch-free clamp (lanes 48-63 duplicate)

        float4 wr[12], wz[12], wn[12];
        const float4* whr = (const float4*)(w_hh + (jj         ) * HDIM);
        const float4* whz = (const float4*)(w_hh + (jj +   HDIM) * HDIM);
        const float4* whn = (const float4*)(w_hh + (jj + 2*HDIM) * HDIM);
        #pragma unroll
        for (int k = 0; k < 12; ++k) { wr[k] = whr[k]; wz[k] = whz[k]; wn[k] = whn[k]; }
        #pragma unroll
        for (int k = 0; k < 12; ++k) { PIN4(wr[k]); PIN4(wz[k]); PIN4(wn[k]); }
        float br = b_hh[jj], bz = b_hh[jj + HDIM], bn = b_hh[jj + 2*HDIM];

        if (j < HDIM) hbuf[1][j] = 0.f;   // h_{-1} = 0 (read at t=0; same-wave ordering)
        float hj = 0.f;

        const int* xrow = x + row * SEQ;
        float xr, xz, xn;
        {
            const float* xg0 = xg_table + xrow[0] * G3;
            xr = xg0[jj]; xz = xg0[jj + HDIM]; xn = xg0[jj + 2*HDIM];
        }

        for (int t = 0; t < SEQ; ++t) {
            // prefetch next step's gate inputs (L2-resident 55 KB table)
            const float* xgn = xg_table + xrow[(t + 1 < SEQ) ? t + 1 : t] * G3;
            float xrn = xgn[jj], xzn = xgn[jj + HDIM], xnn = xgn[jj + 2*HDIM];

            const float4* h4 = (const float4*)hbuf[(t + 1) & 1];  // h_{t-1} parity
            float accr = br, accz = bz, accn = bn;
            #pragma unroll
            for (int k = 0; k < 12; ++k) {
                float4 hh = h4[k];
                accr = fmaf(wr[k].x, hh.x, accr); accr = fmaf(wr[k].y, hh.y, accr);
                accr = fmaf(wr[k].z, hh.z, accr); accr = fmaf(wr[k].w, hh.w, accr);
                accz = fmaf(wz[k].x, hh.x, accz); accz = fmaf(wz[k].y, hh.y, accz);
                accz = fmaf(wz[k].z, hh.z, accz); accz = fmaf(wz[k].w, hh.w, accz);
                accn = fmaf(wn[k].x, hh.x, accn); accn = fmaf(wn[k].y, hh.y, accn);
                accn = fmaf(wn[k].z, hh.z, accn); accn = fmaf(wn[k].w, hh.w, accn);
            }
            float r = sigmoidf_(xr + accr);
            float z = sigmoidf_(xz + accz);
            float n = tanhf_(xn + r * accn);
            float hnew = (1.0f - z) * n + z * hj;
            hj = hnew;
            if (j < HDIM) hbuf[t & 1][j] = hnew;   // publish h_t
            __syncthreads();                       // barrier #t (bottom)
            xr = xrn; xz = xzn; xn = xnn;
        }
        if (j < HDIM) hidden[row * HDIM + j] = hj;
    } else {
        // ================= consumer: logits projection =================
        const int v1 = lane;                                        // rows 0..63
        const int v2 = (lane < VOCAB - 64) ? (lane + 64) : (VOCAB - 1);  // rows 64..94 (clamped dup)
        const bool do2 = (lane < VOCAB - 64);                       // lane < 31

        float4 wa[12], wb[12];
        const float4* wva = (const float4*)(w_out + v1 * HDIM);
        const float4* wvb = (const float4*)(w_out + v2 * HDIM);
        #pragma unroll
        for (int k = 0; k < 12; ++k) { wa[k] = wva[k]; wb[k] = wvb[k]; }
        #pragma unroll
        for (int k = 0; k < 12; ++k) { PIN4(wa[k]); PIN4(wb[k]); }
        float ba = b_out[v1], bb = b_out[v2];

        for (int t = 0; t < SEQ; ++t) {
            __syncthreads();                       // barrier #t (top) — h_t published
            const float4* h4 = (const float4*)hbuf[t & 1];
            float a0 = ba, b0 = bb;
            #pragma unroll
            for (int k = 0; k < 12; ++k) {
                float4 hh = h4[k];
                a0 = fmaf(wa[k].x, hh.x, a0); a0 = fmaf(wa[k].y, hh.y, a0);
                a0 = fmaf(wa[k].z, hh.z, a0); a0 = fmaf(wa[k].w, hh.w, a0);
                b0 = fmaf(wb[k].x, hh.x, b0); b0 = fmaf(wb[k].y, hh.y, b0);
                b0 = fmaf(wb[k].z, hh.z, b0); b0 = fmaf(wb[k].w, hh.w, b0);
            }
            float* po = orow + (long)t * VOCAB;
            po[v1] = a0;                           // lanes 0-63: 256 B contiguous
            if (do2) po[v2] = b0;                  // lanes 0-30: 124 B contiguous
        }
    }
}

extern "C" void kernel_launch(void* const* d_in, const int* in_sizes, int n_in,
                              void* d_out, int out_size, void* d_ws, size_t ws_size,
                              hipStream_t stream) {
    const int*   x     = (const int*)d_in[0];
    const float* emb   = (const float*)d_in[1];
    const float* w_ih  = (const float*)d_in[2];
    const float* w_hh  = (const float*)d_in[3];
    const float* b_ih  = (const float*)d_in[4];
    const float* b_hh  = (const float*)d_in[5];
    const float* w_out = (const float*)d_in[6];
    const float* b_out = (const float*)d_in[7];

    float* out    = (float*)d_out;
    float* hidden = out + (long)BATCH * SEQ * VOCAB;  // second tuple element
    float* xg     = (float*)d_ws;                     // 95*144*4 = 54,720 B

    xg_precompute<<<VOCAB, G3, 0, stream>>>(emb, w_ih, b_ih, xg);
    gru_fused<<<BATCH, 128, 0, stream>>>(x, xg, w_hh, b_hh, w_out, b_out, out, hidden);
}